// Round 15
// baseline (590.100 us; speedup 1.0000x reference)
//
#include <hip/hip_runtime.h>
#include <hip/hip_bf16.h>

#define NFEAT 256
#define NHID 128
#define RELL 86
#define BSHIFT 9                 // bucket = row >> 9 (512 rows)
#define SCAT_TILE 8192           // edges per binscat block (32/thread)
#define TEMPCAP 12288            // per-bucket temp capacity (mean 8163, max ~8600)

typedef __attribute__((ext_vector_type(8))) short short8v;
typedef __attribute__((ext_vector_type(4))) float float4v;

static __device__ __forceinline__ unsigned short f2bf(float f) {
    union { float f; unsigned int u; } v; v.f = f;
    unsigned int r = v.u + 0x7FFF + ((v.u >> 16) & 1);   // RNE
    return (unsigned short)(r >> 16);
}
static __device__ __forceinline__ float asf(unsigned int u) {
    union { unsigned int u; float f; } v; v.u = u; return v.f;
}
static __device__ __forceinline__ float bf2f(unsigned short s) {
    return asf((unsigned int)s << 16);
}

// ---------------------------------------------------------------------------
// Init + weight prep mega-kernel: y<6 -> wt_prep for matrix y;
// y==6 -> zero flag, init bucket cursors, zero compact counter.
// ---------------------------------------------------------------------------
__global__ __launch_bounds__(256) void init_prep(
    const float* __restrict__ W0, const float* __restrict__ W1,
    const float* __restrict__ W2, const float* __restrict__ W3,
    const float* __restrict__ W4, const float* __restrict__ W5,
    unsigned short* __restrict__ T0, unsigned short* __restrict__ T1,
    unsigned short* __restrict__ T2, unsigned short* __restrict__ T3,
    unsigned short* __restrict__ T4, unsigned short* __restrict__ T5,
    int* __restrict__ bcur, int* __restrict__ flag, int* __restrict__ ctr,
    int N)
{
    const int y = blockIdx.y;
    if (y < 6) {
        const int K = (y < 3) ? NFEAT : NHID;
        const float* W = (y == 0) ? W0 : (y == 1) ? W1 : (y == 2) ? W2
                       : (y == 3) ? W3 : (y == 4) ? W4 : W5;
        unsigned short* T = (y == 0) ? T0 : (y == 1) ? T1 : (y == 2) ? T2
                          : (y == 3) ? T3 : (y == 4) ? T4 : T5;
        int i = blockIdx.x * 256 + threadIdx.x;
        if (i < K * 128) {
            int col = i & 127, k = i >> 7;
            T[col * K + k] = f2bf(W[i]);
        }
        return;
    }
    // y == 6: housekeeping
    const int i = blockIdx.x * 256 + threadIdx.x;
    if (i < N) flag[i] = 0;
    if (blockIdx.x == 0) {
        const int t = threadIdx.x;
        bcur[t] = t * TEMPCAP;           // graph o cursors
        bcur[256 + t] = t * TEMPCAP;     // graph s cursors
        if (t == 0) ctr[0] = 0;
    }
}

// ---------------------------------------------------------------------------
// Phase 1: bin edges by row>>9 into fixed-capacity temp slots,
// packed (row&511 | col<<9, val_bits).  (standalone: 0 LDS-heavy state,
// VGPR-light -> high occupancy; round-14 merge with GEMM regressed this)
// ---------------------------------------------------------------------------
__global__ __launch_bounds__(256) void binscat1(
    const int* __restrict__ ro, const int* __restrict__ co,
    const float* __restrict__ vo,
    const int* __restrict__ rs, const int* __restrict__ cs,
    const float* __restrict__ vs,
    int* __restrict__ bcur, int2* __restrict__ temp_o,
    int2* __restrict__ temp_s, int E)
{
    const int g = blockIdx.y;
    const int* rows = g ? rs : ro;
    const int* cols = g ? cs : co;
    const float* vals = g ? vs : vo;
    int* bc = bcur + g * 256;
    int2* temp = g ? temp_s : temp_o;

    __shared__ int hist[256];
    __shared__ int base[256];
    const int t = threadIdx.x;
    hist[t] = 0;
    __syncthreads();

    const int e0 = blockIdx.x * SCAT_TILE;
    int myrow[32];
    #pragma unroll
    for (int i = 0; i < 32; ++i) {
        int e = e0 + i * 256 + t;
        int r = (e < E) ? rows[e] : -1;
        myrow[i] = r;
        if (r >= 0) atomicAdd(&hist[r >> BSHIFT], 1);
    }
    __syncthreads();
    const int h = hist[t];
    if (h > 0) base[t] = atomicAdd(&bc[t], h);
    __syncthreads();
    hist[t] = (h > 0) ? base[t] : 0;     // reuse hist as within-block cursor
    __syncthreads();
    #pragma unroll
    for (int i = 0; i < 32; ++i) {
        const int r = myrow[i];
        if (r >= 0) {
            int e = e0 + i * 256 + t;
            int off = atomicAdd(&hist[r >> BSHIFT], 1);
            temp[off] = make_int2((r & 511) | (cols[e] << BSHIFT),
                                  __float_as_int(vals[e]));
        }
    }
}

// ---------------------------------------------------------------------------
// block 0: bucket-base scan from end cursors (count = bcur[b] - b*TEMPCAP).
// blocks 1..: mark needed rows from idx.
// ---------------------------------------------------------------------------
__global__ __launch_bounds__(512) void scan_mark(
    const int* __restrict__ bcur, int* __restrict__ bbase,
    const int* __restrict__ idx, int* __restrict__ flag, int E, int n2)
{
    if (blockIdx.x == 0) {
        __shared__ int sh[256];
        const int t = threadIdx.x;
        for (int g = 0; g < 2; ++g) {
            int v = 0;
            if (t < 256) { v = bcur[g * 256 + t] - t * TEMPCAP; sh[t] = v; }
            __syncthreads();
            for (int off = 1; off < 256; off <<= 1) {
                int u = (t < 256 && t >= off) ? sh[t - off] : 0;
                __syncthreads();
                if (t < 256) sh[t] += u;
                __syncthreads();
            }
            if (t < 256) {
                bbase[g * 257 + t] = sh[t] - v;   // exclusive
                if (t == 255) bbase[g * 257 + 256] = E;
            }
            __syncthreads();
        }
    } else {
        int i = (blockIdx.x - 1) * 512 + threadIdx.x;
        if (i < n2) flag[idx[i]] = 1;
    }
}

// ---------------------------------------------------------------------------
// y<2: per-bucket local counting sort (single temp read; edges staged in
// registers via static unroll). Writes rp + final CSR ev.
// y==2: compact marked rows -> rlist/inv/ctr.
// ---------------------------------------------------------------------------
__global__ __launch_bounds__(512) void bs2_compact(
    const int* __restrict__ bbase,
    const int2* __restrict__ temp_o, const int2* __restrict__ temp_s,
    int* __restrict__ rp_o, int* __restrict__ rp_s,
    int2* __restrict__ ev_o, int2* __restrict__ ev_s,
    const int* __restrict__ flag, int* __restrict__ rlist,
    int* __restrict__ inv, int* __restrict__ ctr, int N)
{
    if (blockIdx.y == 2) {
        int r = blockIdx.x * 512 + threadIdx.x;
        if (r < N && flag[r]) {
            int i = atomicAdd(ctr, 1);
            rlist[i] = r;
            inv[r] = i;
        }
        return;
    }
    const int g = blockIdx.y;
    const int2* temp = g ? temp_s : temp_o;
    int2* ev = g ? ev_s : ev_o;
    int* rp = g ? rp_s : rp_o;
    const int* bb = bbase + g * 257;

    __shared__ int lcnt[512];
    __shared__ int lpre[512];
    const int b = blockIdx.x;
    const int r0 = b << BSHIFT;
    const int t = threadIdx.x;
    const int e0 = bb[b];                      // final CSR base
    const int cntE = bb[b + 1] - e0;           // edges in bucket (<= TEMPCAP)
    const int t0 = b * TEMPCAP;                // temp base

    int2 myed[24];                             // 24*512 = TEMPCAP
    lcnt[t] = 0;
    __syncthreads();
    #pragma unroll
    for (int i = 0; i < 24; ++i) {
        int k = i * 512 + t;
        int2 pk = make_int2(0, 0);
        if (k < cntE) {
            pk = temp[t0 + k];
            atomicAdd(&lcnt[pk.x & 511], 1);
        }
        myed[i] = pk;
    }
    __syncthreads();
    const int v = lcnt[t];
    lpre[t] = v;
    __syncthreads();
    for (int off = 1; off < 512; off <<= 1) {
        int u = (t >= off) ? lpre[t - off] : 0;
        __syncthreads();
        lpre[t] += u;
        __syncthreads();
    }
    const int base = e0 + lpre[t] - v;
    const int r = r0 + t;
    if (r <= N) rp[r] = base;
    __syncthreads();
    lcnt[t] = base;                            // row cursors
    __syncthreads();
    #pragma unroll
    for (int i = 0; i < 24; ++i) {
        int k = i * 512 + t;
        if (k < cntE) {
            int2 pk = myed[i];
            int q = atomicAdd(&lcnt[pk.x & 511], 1);
            ev[q] = make_int2(pk.x >> BSHIFT, pk.y);
        }
    }
}

// ---------------------------------------------------------------------------
// Fused MFMA GEMM: S_m = X @ W_m for NM matrices, X staged ONCE (full K) in LDS.
// 4 waves over a 2x2 (row-half x col-half) grid: 6 LDS b128 reads per 8 MFMA.
// ---------------------------------------------------------------------------
template <int K, int NM, bool XBF>
__global__ __launch_bounds__(256) void gemm_fused(
    const void* __restrict__ Xv,
    const unsigned short* __restrict__ Wt0, unsigned short* __restrict__ S0,
    const unsigned short* __restrict__ Wt1, unsigned short* __restrict__ S1,
    const unsigned short* __restrict__ Wt2, unsigned short* __restrict__ S2,
    int Nrows)
{
    constexpr int AST = K + 8;
    __shared__ unsigned short As[64 * AST];
    __shared__ unsigned short Bs[128 * 72];

    const int t = threadIdx.x;
    const int l = t & 63;
    const int w = t >> 6;
    const int row_in = l & 15;
    const int kgrp = l >> 4;        // 0..3
    const int rhalf = w & 1;
    const int chalf = w >> 1;
    const int row0 = blockIdx.x * 64;

    {
        constexpr int QPR = K / 4;
        #pragma unroll
        for (int it = 0; it < 64 * QPR / 256; ++it) {
            int i = t + it * 256;
            int r = i / QPR, c4 = i % QPR;
            int gr = row0 + r;
            if (XBF) {
                ushort4 v = make_ushort4(0, 0, 0, 0);
                if (gr < Nrows)
                    v = *(const ushort4*)((const unsigned short*)Xv + (size_t)gr * K + c4 * 4);
                *(ushort4*)&As[r * AST + c4 * 4] = v;
            } else {
                float4 v = make_float4(0.f, 0.f, 0.f, 0.f);
                if (gr < Nrows)
                    v = *(const float4*)((const float*)Xv + (size_t)gr * K + c4 * 4);
                ushort4 b4;
                b4.x = f2bf(v.x); b4.y = f2bf(v.y); b4.z = f2bf(v.z); b4.w = f2bf(v.w);
                *(ushort4*)&As[r * AST + c4 * 4] = b4;
            }
        }
    }

    #pragma unroll
    for (int m = 0; m < NM; ++m) {
        const unsigned short* Wt = (m == 0) ? Wt0 : ((m == 1) ? Wt1 : Wt2);
        unsigned short* S = (m == 0) ? S0 : ((m == 1) ? S1 : S2);
        float4v acc[2][4];
        #pragma unroll
        for (int mi = 0; mi < 2; ++mi)
            #pragma unroll
            for (int n = 0; n < 4; ++n) acc[mi][n] = (float4v)(0.f);

        for (int kt = 0; kt < K / 64; ++kt) {
            __syncthreads();
            #pragma unroll
            for (int it = 0; it < 8; ++it) {
                int i = t + it * 256;
                int r = i >> 4, c4 = i & 15;
                *(ushort4*)&Bs[r * 72 + c4 * 4] =
                    *(const ushort4*)(Wt + (size_t)r * K + kt * 64 + c4 * 4);
            }
            __syncthreads();
            #pragma unroll
            for (int kc = 0; kc < 2; ++kc) {
                short8v a[2], b[4];
                #pragma unroll
                for (int mi = 0; mi < 2; ++mi) {
                    const unsigned short* pa =
                        &As[(rhalf * 32 + mi * 16 + row_in) * AST + kt * 64 + kc * 32 + kgrp * 8];
                    ((uint2*)&a[mi])[0] = *(const uint2*)pa;
                    ((uint2*)&a[mi])[1] = *(const uint2*)(pa + 4);
                }
                #pragma unroll
                for (int n = 0; n < 4; ++n) {
                    const unsigned short* pb =
                        &Bs[(chalf * 64 + n * 16 + row_in) * 72 + kc * 32 + kgrp * 8];
                    ((uint2*)&b[n])[0] = *(const uint2*)pb;
                    ((uint2*)&b[n])[1] = *(const uint2*)(pb + 4);
                }
                #pragma unroll
                for (int mi = 0; mi < 2; ++mi)
                    #pragma unroll
                    for (int n = 0; n < 4; ++n)
                        acc[mi][n] = __builtin_amdgcn_mfma_f32_16x16x32_bf16(
                            a[mi], b[n], acc[mi][n], 0, 0, 0);
            }
        }
        #pragma unroll
        for (int mi = 0; mi < 2; ++mi)
            #pragma unroll
            for (int n = 0; n < 4; ++n)
                #pragma unroll
                for (int r = 0; r < 4; ++r) {
                    int gr = row0 + rhalf * 32 + mi * 16 + kgrp * 4 + r;
                    int gc = chalf * 64 + n * 16 + row_in;
                    if (gr < Nrows) S[(size_t)gr * 128 + gc] = f2bf(acc[mi][n][r]);
                }
    }
}

// ---------------------------------------------------------------------------
// GEMM for s_x: sxb = relu(Yo @ Wt4 + Zs + b1 + b2), all K=128, bf16 in/out.
// ---------------------------------------------------------------------------
__global__ __launch_bounds__(256) void gemm_sx(
    const unsigned short* __restrict__ Yo,
    const unsigned short* __restrict__ Wt,
    const unsigned short* __restrict__ Zs,
    const float* __restrict__ b1, const float* __restrict__ b2,
    unsigned short* __restrict__ sxb, int Nrows)
{
    constexpr int AST = 136;
    __shared__ unsigned short As[64 * AST];
    __shared__ unsigned short Bs[128 * 72];

    const int t = threadIdx.x;
    const int l = t & 63;
    const int w = t >> 6;
    const int row_in = l & 15;
    const int kgrp = l >> 4;
    const int rhalf = w & 1;
    const int chalf = w >> 1;
    const int row0 = blockIdx.x * 64;

    #pragma unroll
    for (int it = 0; it < 8; ++it) {        // 64 rows * 32 quads / 256
        int i = t + it * 256;
        int r = i >> 5, c4 = i & 31;
        int gr = row0 + r;
        ushort4 v = make_ushort4(0, 0, 0, 0);
        if (gr < Nrows) v = *(const ushort4*)(Yo + (size_t)gr * 128 + c4 * 4);
        *(ushort4*)&As[r * AST + c4 * 4] = v;
    }

    float4v acc[2][4];
    #pragma unroll
    for (int mi = 0; mi < 2; ++mi)
        #pragma unroll
        for (int n = 0; n < 4; ++n) acc[mi][n] = (float4v)(0.f);

    for (int kt = 0; kt < 2; ++kt) {
        __syncthreads();
        #pragma unroll
        for (int it = 0; it < 8; ++it) {
            int i = t + it * 256;
            int r = i >> 4, c4 = i & 15;
            *(ushort4*)&Bs[r * 72 + c4 * 4] =
                *(const ushort4*)(Wt + (size_t)r * 128 + kt * 64 + c4 * 4);
        }
        __syncthreads();
        #pragma unroll
        for (int kc = 0; kc < 2; ++kc) {
            short8v a[2], b[4];
            #pragma unroll
            for (int mi = 0; mi < 2; ++mi) {
                const unsigned short* pa =
                    &As[(rhalf * 32 + mi * 16 + row_in) * AST + kt * 64 + kc * 32 + kgrp * 8];
                ((uint2*)&a[mi])[0] = *(const uint2*)pa;
                ((uint2*)&a[mi])[1] = *(const uint2*)(pa + 4);
            }
            #pragma unroll
            for (int n = 0; n < 4; ++n) {
                const unsigned short* pb =
                    &Bs[(chalf * 64 + n * 16 + row_in) * 72 + kc * 32 + kgrp * 8];
                ((uint2*)&b[n])[0] = *(const uint2*)pb;
                ((uint2*)&b[n])[1] = *(const uint2*)(pb + 4);
            }
            #pragma unroll
            for (int mi = 0; mi < 2; ++mi)
                #pragma unroll
                for (int n = 0; n < 4; ++n)
                    acc[mi][n] = __builtin_amdgcn_mfma_f32_16x16x32_bf16(
                        a[mi], b[n], acc[mi][n], 0, 0, 0);
        }
    }
    #pragma unroll
    for (int mi = 0; mi < 2; ++mi)
        #pragma unroll
        for (int n = 0; n < 4; ++n)
            #pragma unroll
            for (int r = 0; r < 4; ++r) {
                int gr = row0 + rhalf * 32 + mi * 16 + kgrp * 4 + r;
                int gc = chalf * 64 + n * 16 + row_in;
                if (gr < Nrows) {
                    float vfin = acc[mi][n][r] + bf2f(Zs[(size_t)gr * 128 + gc])
                               + b1[gc] + b2[gc];
                    sxb[(size_t)gr * 128 + gc] = f2bf(fmaxf(vfin, 0.f));
                }
            }
}

// ---------------------------------------------------------------------------
// spmm gather helpers
// ---------------------------------------------------------------------------
#define GS(S, pk) (*(const unsigned*)((S) + ((size_t)(pk).x << 7) + l2))
#define ACCV(pk, uu) { float vv = __int_as_float((pk).y); \
    ax = fmaf(vv, asf((uu) << 16), ax); ay = fmaf(vv, asf((uu) & 0xffff0000u), ay); }

// ---------------------------------------------------------------------------
// spmm1: fused dual-graph CSR SpMM with bias+relu, bf16 out (layer 1).
// ---------------------------------------------------------------------------
__global__ __launch_bounds__(256) void spmm1_k(
    const int* __restrict__ rp_a, const int2* __restrict__ ev_a,
    const unsigned short* __restrict__ Sa,
    const int* __restrict__ rp_b, const int2* __restrict__ ev_b,
    const unsigned short* __restrict__ Sb,
    const float* __restrict__ b1, const float* __restrict__ b2,
    unsigned short* __restrict__ out, int N)
{
    const int row = blockIdx.x * 4 + (threadIdx.x >> 6);
    if (row >= N) return;
    const int l2 = (threadIdx.x & 63) << 1;

    float2 bv1 = *(const float2*)(b1 + l2);
    float2 bv2 = *(const float2*)(b2 + l2);
    float ax = bv1.x + bv2.x;
    float ay = bv1.y + bv2.y;

    #pragma unroll
    for (int g = 0; g < 2; ++g) {
        const int* __restrict__ rp = g ? rp_b : rp_a;
        const int2* __restrict__ ev = g ? ev_b : ev_a;
        const unsigned short* __restrict__ S = g ? Sb : Sa;
        int e = rp[row];
        const int e1 = rp[row + 1];
        for (; e + 8 <= e1; e += 8) {
            const int2 p0 = ev[e], p1 = ev[e+1], p2 = ev[e+2], p3 = ev[e+3];
            const int2 p4 = ev[e+4], p5 = ev[e+5], p6 = ev[e+6], p7 = ev[e+7];
            const unsigned u0 = GS(S,p0), u1 = GS(S,p1), u2 = GS(S,p2), u3 = GS(S,p3);
            const unsigned u4 = GS(S,p4), u5 = GS(S,p5), u6 = GS(S,p6), u7 = GS(S,p7);
            ACCV(p0,u0) ACCV(p1,u1) ACCV(p2,u2) ACCV(p3,u3)
            ACCV(p4,u4) ACCV(p5,u5) ACCV(p6,u6) ACCV(p7,u7)
        }
        for (; e + 4 <= e1; e += 4) {
            const int2 p0 = ev[e], p1 = ev[e+1], p2 = ev[e+2], p3 = ev[e+3];
            const unsigned u0 = GS(S,p0), u1 = GS(S,p1), u2 = GS(S,p2), u3 = GS(S,p3);
            ACCV(p0,u0) ACCV(p1,u1) ACCV(p2,u2) ACCV(p3,u3)
        }
        for (; e < e1; ++e) {
            const int2 p0 = ev[e];
            const unsigned u0 = GS(S,p0);
            ACCV(p0,u0)
        }
    }
    ax = fmaxf(ax, 0.f); ay = fmaxf(ay, 0.f);
    unsigned pk = (unsigned)f2bf(ax) | ((unsigned)f2bf(ay) << 16);
    ((unsigned*)out)[((size_t)row << 6) + (l2 >> 1)] = pk;
}

// ---------------------------------------------------------------------------
// spmm_split: Yo = A_o * oxb, Zs = A_s * tabC (no bias, no relu), bf16 out.
// ---------------------------------------------------------------------------
__global__ __launch_bounds__(256) void spmm_split(
    const int* __restrict__ rp_a, const int2* __restrict__ ev_a,
    const unsigned short* __restrict__ Sa,
    const int* __restrict__ rp_b, const int2* __restrict__ ev_b,
    const unsigned short* __restrict__ Sb,
    unsigned short* __restrict__ Yo, unsigned short* __restrict__ Zs, int N)
{
    const int row = blockIdx.x * 4 + (threadIdx.x >> 6);
    if (row >= N) return;
    const int l2 = (threadIdx.x & 63) << 1;

    #pragma unroll
    for (int g = 0; g < 2; ++g) {
        const int* __restrict__ rp = g ? rp_b : rp_a;
        const int2* __restrict__ ev = g ? ev_b : ev_a;
        const unsigned short* __restrict__ S = g ? Sb : Sa;
        unsigned short* __restrict__ out = g ? Zs : Yo;
        float ax = 0.f, ay = 0.f;
        int e = rp[row];
        const int e1 = rp[row + 1];
        for (; e + 8 <= e1; e += 8) {
            const int2 p0 = ev[e], p1 = ev[e+1], p2 = ev[e+2], p3 = ev[e+3];
            const int2 p4 = ev[e+4], p5 = ev[e+5], p6 = ev[e+6], p7 = ev[e+7];
            const unsigned u0 = GS(S,p0), u1 = GS(S,p1), u2 = GS(S,p2), u3 = GS(S,p3);
            const unsigned u4 = GS(S,p4), u5 = GS(S,p5), u6 = GS(S,p6), u7 = GS(S,p7);
            ACCV(p0,u0) ACCV(p1,u1) ACCV(p2,u2) ACCV(p3,u3)
            ACCV(p4,u4) ACCV(p5,u5) ACCV(p6,u6) ACCV(p7,u7)
        }
        for (; e + 4 <= e1; e += 4) {
            const int2 p0 = ev[e], p1 = ev[e+1], p2 = ev[e+2], p3 = ev[e+3];
            const unsigned u0 = GS(S,p0), u1 = GS(S,p1), u2 = GS(S,p2), u3 = GS(S,p3);
            ACCV(p0,u0) ACCV(p1,u1) ACCV(p2,u2) ACCV(p3,u3)
        }
        for (; e < e1; ++e) {
            const int2 p0 = ev[e];
            const unsigned u0 = GS(S,p0);
            ACCV(p0,u0)
        }
        unsigned pk = (unsigned)f2bf(ax) | ((unsigned)f2bf(ay) << 16);
        ((unsigned*)out)[((size_t)row << 6) + (l2 >> 1)] = pk;
    }
}

// ---------------------------------------------------------------------------
// sparse_h: FUSED spmm_s_sparse + gemm_h.
// Per block of 64 compact rows: As2 = A_s*sxb (gathered into LDS, per-wave),
// As1 = Yo[rlist] staged; then h = As1@Wt5 + As2@Wt6 + b1 + b2.
// ---------------------------------------------------------------------------
__global__ __launch_bounds__(256) void sparse_h(
    const int* __restrict__ rp, const int2* __restrict__ ev,
    const unsigned short* __restrict__ S,
    const unsigned short* __restrict__ Yo,
    const int* __restrict__ rlist, const int* __restrict__ pcnt,
    const unsigned short* __restrict__ Wt5, const unsigned short* __restrict__ Wt6,
    const float* __restrict__ b1, const float* __restrict__ b2,
    float* __restrict__ h)
{
    constexpr int AST = 136;
    __shared__ unsigned short As1[64 * AST];
    __shared__ unsigned short As2[64 * AST];
    __shared__ unsigned short Bs[128 * 72];

    const int cnt = *pcnt;
    const int row0 = blockIdx.x * 64;
    if (row0 >= cnt) return;

    const int t = threadIdx.x;
    const int l = t & 63;
    const int wv = t >> 6;
    const int l2 = l << 1;

    // As1: Yo[rlist] staging
    #pragma unroll
    for (int it = 0; it < 8; ++it) {
        int i = t + it * 256;
        int r = i >> 5, c4 = i & 31;
        int gr = row0 + r;
        ushort4 v1 = make_ushort4(0, 0, 0, 0);
        if (gr < cnt) {
            int src = rlist[gr];
            v1 = *(const ushort4*)(Yo + (size_t)src * 128 + c4 * 4);
        }
        *(ushort4*)&As1[r * AST + c4 * 4] = v1;
    }

    // As2: A_s * sxb, 16 rows per wave (one wave-row at a time)
    for (int i = 0; i < 16; ++i) {
        const int lr = wv * 16 + i;
        const int gr = row0 + lr;
        float ax = 0.f, ay = 0.f;
        if (gr < cnt) {
            const int row = rlist[gr];
            int e = rp[row];
            const int e1 = rp[row + 1];
            for (; e + 8 <= e1; e += 8) {
                const int2 p0 = ev[e], p1 = ev[e+1], p2 = ev[e+2], p3 = ev[e+3];
                const int2 p4 = ev[e+4], p5 = ev[e+5], p6 = ev[e+6], p7 = ev[e+7];
                const unsigned u0 = GS(S,p0), u1 = GS(S,p1), u2 = GS(S,p2), u3 = GS(S,p3);
                const unsigned u4 = GS(S,p4), u5 = GS(S,p5), u6 = GS(S,p6), u7 = GS(S,p7);
                ACCV(p0,u0) ACCV(p1,u1) ACCV(p2,u2) ACCV(p3,u3)
                ACCV(p4,u4) ACCV(p5,u5) ACCV(p6,u6) ACCV(p7,u7)
            }
            for (; e + 4 <= e1; e += 4) {
                const int2 p0 = ev[e], p1 = ev[e+1], p2 = ev[e+2], p3 = ev[e+3];
                const unsigned u0 = GS(S,p0), u1 = GS(S,p1), u2 = GS(S,p2), u3 = GS(S,p3);
                ACCV(p0,u0) ACCV(p1,u1) ACCV(p2,u2) ACCV(p3,u3)
            }
            for (; e < e1; ++e) {
                const int2 p0 = ev[e];
                const unsigned u0 = GS(S,p0);
                ACCV(p0,u0)
            }
        }
        As2[lr * AST + l2] = f2bf(ax);
        As2[lr * AST + l2 + 1] = f2bf(ay);
    }
    __syncthreads();

    // GEMM: h = As1@Wt5 + As2@Wt6 + b1 + b2
    const int row_in = l & 15;
    const int kgrp = l >> 4;
    const int rhalf = wv & 1;
    const int chalf = wv >> 1;

    float4v acc[2][4];
    #pragma unroll
    for (int mi = 0; mi < 2; ++mi)
        #pragma unroll
        for (int n = 0; n < 4; ++n) acc[mi][n] = (float4v)(0.f);

    #pragma unroll
    for (int pp = 0; pp < 2; ++pp) {
        const unsigned short* Wt = pp ? Wt6 : Wt5;
        const unsigned short* As = pp ? As2 : As1;
        for (int kt = 0; kt < 2; ++kt) {
            __syncthreads();
            #pragma unroll
            for (int it = 0; it < 8; ++it) {
                int i = t + it * 256;
                int r = i >> 4, c4 = i & 15;
                *(ushort4*)&Bs[r * 72 + c4 * 4] =
                    *(const ushort4*)(Wt + (size_t)r * 128 + kt * 64 + c4 * 4);
            }
            __syncthreads();
            #pragma unroll
            for (int kc = 0; kc < 2; ++kc) {
                short8v a[2], b[4];
                #pragma unroll
                for (int mi = 0; mi < 2; ++mi) {
                    const unsigned short* pa =
                        &As[(rhalf * 32 + mi * 16 + row_in) * AST + kt * 64 + kc * 32 + kgrp * 8];
                    ((uint2*)&a[mi])[0] = *(const uint2*)pa;
                    ((uint2*)&a[mi])[1] = *(const uint2*)(pa + 4);
                }
                #pragma unroll
                for (int n = 0; n < 4; ++n) {
                    const unsigned short* pb =
                        &Bs[(chalf * 64 + n * 16 + row_in) * 72 + kc * 32 + kgrp * 8];
                    ((uint2*)&b[n])[0] = *(const uint2*)pb;
                    ((uint2*)&b[n])[1] = *(const uint2*)(pb + 4);
                }
                #pragma unroll
                for (int mi = 0; mi < 2; ++mi)
                    #pragma unroll
                    for (int n = 0; n < 4; ++n)
                        acc[mi][n] = __builtin_amdgcn_mfma_f32_16x16x32_bf16(
                            a[mi], b[n], acc[mi][n], 0, 0, 0);
            }
        }
    }
    #pragma unroll
    for (int mi = 0; mi < 2; ++mi)
        #pragma unroll
        for (int n = 0; n < 4; ++n)
            #pragma unroll
            for (int r = 0; r < 4; ++r) {
                int gr = row0 + rhalf * 32 + mi * 16 + kgrp * 4 + r;
                int gc = chalf * 64 + n * 16 + row_in;
                if (gr < cnt)
                    h[(size_t)gr * 128 + gc] = acc[mi][n][r] + b1[gc] + b2[gc];
            }
}
#undef GS
#undef ACCV

// ---------------------------------------------------------------------------
// Fused decoder: o1 tile stays in LDS between the two small GEMMs.
// ---------------------------------------------------------------------------
__global__ __launch_bounds__(128) void dec_fused(
    const float* __restrict__ h, const int* __restrict__ inv,
    const int* __restrict__ idx0, const int* __restrict__ idx1,
    const float* __restrict__ Wd1, const float* __restrict__ bd1,
    const float* __restrict__ Wd2, const float* __restrict__ bd2,
    float* __restrict__ out, int B)
{
    __shared__ __align__(16) float fs[16 * 256];
    __shared__ __align__(16) float os[16 * 128];
    const int t = threadIdx.x;
    const int b0 = blockIdx.x * 16;
    #pragma unroll
    for (int r = 0; r < 16; ++r) {
        const int b = b0 + r;
        fs[r * 256 + t]       = h[(long)inv[idx0[b]] * 128 + t];
        fs[r * 256 + 128 + t] = h[(long)inv[idx1[b]] * 128 + t];
    }
    __syncthreads();

    {
        const float4* fs4 = (const float4*)fs;
        float acc[16];
        #pragma unroll
        for (int r = 0; r < 16; ++r) acc[r] = 0.f;
        for (int kc = 0; kc < 64; ++kc) {
            const float w0 = Wd1[(kc * 4 + 0) * 128 + t];
            const float w1 = Wd1[(kc * 4 + 1) * 128 + t];
            const float w2 = Wd1[(kc * 4 + 2) * 128 + t];
            const float w3 = Wd1[(kc * 4 + 3) * 128 + t];
            #pragma unroll
            for (int r = 0; r < 16; ++r) {
                const float4 xv = fs4[r * 64 + kc];
                acc[r] = fmaf(xv.x, w0, acc[r]);
                acc[r] = fmaf(xv.y, w1, acc[r]);
                acc[r] = fmaf(xv.z, w2, acc[r]);
                acc[r] = fmaf(xv.w, w3, acc[r]);
            }
        }
        #pragma unroll
        for (int r = 0; r < 16; ++r)
            os[r * 128 + t] = acc[r] + bd1[t];
    }
    __syncthreads();

    {
        const float4* os4 = (const float4*)os;
        float acc[16];
        #pragma unroll
        for (int r = 0; r < 16; ++r) acc[r] = 0.f;
        const bool act = (t < RELL);
        for (int kc = 0; kc < 32; ++kc) {
            const float w0 = act ? Wd2[(kc * 4 + 0) * RELL + t] : 0.f;
            const float w1 = act ? Wd2[(kc * 4 + 1) * RELL + t] : 0.f;
            const float w2 = act ? Wd2[(kc * 4 + 2) * RELL + t] : 0.f;
            const float w3 = act ? Wd2[(kc * 4 + 3) * RELL + t] : 0.f;
            #pragma unroll
            for (int r = 0; r < 16; ++r) {
                const float4 xv = os4[r * 32 + kc];
                acc[r] = fmaf(xv.x, w0, acc[r]);
                acc[r] = fmaf(xv.y, w1, acc[r]);
                acc[r] = fmaf(xv.z, w2, acc[r]);
                acc[r] = fmaf(xv.w, w3, acc[r]);
            }
        }
        if (act) {
            #pragma unroll
            for (int r = 0; r < 16; ++r)
                out[(long)(b0 + r) * RELL + t] = acc[r] + bd2[t];
        }
    }
}

extern "C" void kernel_launch(void* const* d_in, const int* in_sizes, int n_in,
                              void* d_out, int out_size, void* d_ws, size_t ws_size,
                              hipStream_t stream) {
    const float* x      = (const float*)d_in[0];
    const int*   o_rows = (const int*)  d_in[1];
    const int*   o_cols = (const int*)  d_in[2];
    const float* o_vals = (const float*)d_in[3];
    const int*   s_rows = (const int*)  d_in[4];
    const int*   s_cols = (const int*)  d_in[5];
    const float* s_vals = (const float*)d_in[6];
    const int*   idx    = (const int*)  d_in[7];
    const float* W_ogc1  = (const float*)d_in[8];   const float* b_ogc1  = (const float*)d_in[9];
    const float* W_sgc1o = (const float*)d_in[10];  const float* b_sgc1o = (const float*)d_in[11];
    const float* W_sgc1  = (const float*)d_in[12];  const float* b_sgc1  = (const float*)d_in[13];
    const float* W_ogc1s = (const float*)d_in[14];  const float* b_ogc1s = (const float*)d_in[15];
    const float* W_ogc2  = (const float*)d_in[16];  const float* b_ogc2  = (const float*)d_in[17];
    const float* W_sgc2o = (const float*)d_in[18];  const float* b_sgc2o = (const float*)d_in[19];
    const float* W_dec1  = (const float*)d_in[20];  const float* b_dec1  = (const float*)d_in[21];
    const float* W_dec2  = (const float*)d_in[22];  const float* b_dec2  = (const float*)d_in[23];

    const int N = in_sizes[0] / NFEAT;   // 100000
    const int E = in_sizes[1];           // 1600000
    const int B = in_sizes[7] / 2;       // 16384
    const int* idx0 = idx;
    const int* idx1 = idx + B;

    // ---- workspace layout (float units) ----
    float* p = (float*)d_ws;
    const size_t N64 = (size_t)N * 64;    // one bf16 [N,128] table in float units
    float* h    = p;  p += (size_t)2 * B * 128;      // compact fp32 [<=2B,128]
    unsigned short* oxb  = (unsigned short*)p; p += N64;   // o_x bf16
    unsigned short* sxb  = (unsigned short*)p; p += N64;   // s_x bf16
    unsigned short* tabA = (unsigned short*)p; p += N64;
    unsigned short* tabB = (unsigned short*)p; p += N64;
    unsigned short* tabC = (unsigned short*)p; p += N64;
    unsigned short* Yo   = (unsigned short*)p; p += N64;   // A_o * o_x
    unsigned short* Zs   = (unsigned short*)p; p += N64;   // A_s * tabC
    unsigned short* wt1 = (unsigned short*)p; p += 16384;   // [128,256] bf16
    unsigned short* wt2 = (unsigned short*)p; p += 16384;
    unsigned short* wt3 = (unsigned short*)p; p += 16384;
    unsigned short* wt4 = (unsigned short*)p; p += 8192;    // [128,128] bf16
    unsigned short* wt5 = (unsigned short*)p; p += 8192;
    unsigned short* wt6 = (unsigned short*)p; p += 8192;
    int* rp_o = (int*)p; p += (size_t)N + 2;
    int* rp_s = (int*)p; p += (size_t)N + 2;
    int2* ev_o = (int2*)p; p += 2 * (size_t)E;
    int2* ev_s = (int2*)p; p += 2 * (size_t)E;
    int* bbase = (int*)p; p += 516;                  // [2][257] bucket bases
    int* bcur  = (int*)p; p += 512;                  // [2][256] bucket cursors
    int* flag  = (int*)p; p += (size_t)N;            // needed-row flags
    int* rlist = (int*)p; p += (size_t)N;            // compact row list
    int* inv   = (int*)p; p += (size_t)N;            // node -> compact index
    int* ctr   = (int*)p; p += 2;                    // compact count
    // temp binning buffers alias Yo/Zs (dead until spmm_split)
    int2* temp_o = (int2*)Yo;                        // 256*TEMPCAP int2 = 25.2 MB
    int2* temp_s = (int2*)Zs;

    const int gM64 = (N + 63) / 64;       // 1563
    const int gR = (N + 3) / 4;           // 25000
    const int gH = (2 * B + 63) / 64;     // 512
    const int gB = B / 16;                // 1024
    const int gT = (E + SCAT_TILE - 1) / SCAT_TILE;                   // 196
    const int gBuck = (N + (1 << BSHIFT) - 1) >> BSHIFT;              // 196
    const int gFlag = (N + 255) / 256;                                // 391
    const int gMark = (2 * B + 511) / 512;                            // 64

    // ---- init + weight prep
    init_prep<<<dim3(gFlag, 7), 256, 0, stream>>>(
        W_ogc1, W_sgc1o, W_sgc1, W_ogc1s, W_ogc2, W_sgc2o,
        wt1, wt2, wt3, wt4, wt5, wt6, bcur, flag, ctr, N);

    // ---- CSR build (standalone lightweight kernels; merge regressed in R14)
    binscat1<<<dim3(gT, 2), 256, 0, stream>>>(o_rows, o_cols, o_vals,
                                              s_rows, s_cols, s_vals,
                                              bcur, temp_o, temp_s, E);
    scan_mark<<<1 + gMark, 512, 0, stream>>>(bcur, bbase, idx, flag, E, 2 * B);
    bs2_compact<<<dim3(gBuck, 3), 512, 0, stream>>>(
        bbase, temp_o, temp_s, rp_o, rp_s, ev_o, ev_s,
        flag, rlist, inv, ctr, N);

    // ---- Layer 1 GEMMs (x read once): tabA=x@W_ogc1, tabB=x@W_sgc1o, tabC=x@W_sgc1
    gemm_fused<NFEAT, 3, false><<<gM64, 256, 0, stream>>>(
        x, wt1, tabA, wt2, tabB, wt3, tabC, N);

    // ---- Layer 1 spmm: o_x = relu(A_o*tabA + A_s*tabB + b)
    spmm1_k<<<gR, 256, 0, stream>>>(rp_o, ev_o, tabA, rp_s, ev_s, tabB,
                                    b_ogc1, b_sgc1o, oxb, N);

    // ---- spmm_split: Yo = A_o*o_x, Zs = A_s*tabC  (serves layers 2 AND 3)
    spmm_split<<<gR, 256, 0, stream>>>(rp_o, ev_o, oxb, rp_s, ev_s, tabC,
                                       Yo, Zs, N);

    // ---- s_x = relu(Yo@W_ogc1s + Zs + b_ogc1s + b_sgc1)
    gemm_sx<<<gM64, 256, 0, stream>>>(Yo, wt4, Zs, b_ogc1s, b_sgc1, sxb, N);

    // ---- fused: Ys2 = A_s*s_x (in LDS) ; h = Yo[rlist]@W_ogc2 + Ys2@W_sgc2o + b
    sparse_h<<<gH, 256, 0, stream>>>(rp_s, ev_s, sxb, Yo, rlist, ctr,
                                     wt5, wt6, b_ogc2, b_sgc2o, h);

    // ---- Fused decoder
    dec_fused<<<gB, 128, 0, stream>>>(h, inv, idx0, idx1,
                                      W_dec1, b_dec1, W_dec2, b_dec2,
                                      (float*)d_out, B);
}

// Round 16
// 558.193 us; speedup vs baseline: 1.0572x; 1.0572x over previous
//
#include <hip/hip_runtime.h>
#include <hip/hip_bf16.h>

#define NFEAT 256
#define NHID 128
#define RELL 86
#define BSHIFT 9                 // bucket = row >> 9 (512 rows)
#define SCAT_TILE 8192           // edges per binscat block (32/thread)
#define TEMPCAP 12288            // per-bucket temp capacity (mean 8163, max ~8600)

typedef __attribute__((ext_vector_type(8))) short short8v;
typedef __attribute__((ext_vector_type(4))) float float4v;

static __device__ __forceinline__ unsigned short f2bf(float f) {
    union { float f; unsigned int u; } v; v.f = f;
    unsigned int r = v.u + 0x7FFF + ((v.u >> 16) & 1);   // RNE
    return (unsigned short)(r >> 16);
}
static __device__ __forceinline__ float asf(unsigned int u) {
    union { unsigned int u; float f; } v; v.u = u; return v.f;
}
static __device__ __forceinline__ float bf2f(unsigned short s) {
    return asf((unsigned int)s << 16);
}

// ---------------------------------------------------------------------------
// Init + weight prep mega-kernel: y<6 -> wt_prep for matrix y;
// y==6 -> zero flag, init bucket cursors, zero compact counter.
// ---------------------------------------------------------------------------
__global__ __launch_bounds__(256) void init_prep(
    const float* __restrict__ W0, const float* __restrict__ W1,
    const float* __restrict__ W2, const float* __restrict__ W3,
    const float* __restrict__ W4, const float* __restrict__ W5,
    unsigned short* __restrict__ T0, unsigned short* __restrict__ T1,
    unsigned short* __restrict__ T2, unsigned short* __restrict__ T3,
    unsigned short* __restrict__ T4, unsigned short* __restrict__ T5,
    int* __restrict__ bcur, int* __restrict__ flag, int* __restrict__ ctr,
    int N)
{
    const int y = blockIdx.y;
    if (y < 6) {
        const int K = (y < 3) ? NFEAT : NHID;
        const float* W = (y == 0) ? W0 : (y == 1) ? W1 : (y == 2) ? W2
                       : (y == 3) ? W3 : (y == 4) ? W4 : W5;
        unsigned short* T = (y == 0) ? T0 : (y == 1) ? T1 : (y == 2) ? T2
                          : (y == 3) ? T3 : (y == 4) ? T4 : T5;
        int i = blockIdx.x * 256 + threadIdx.x;
        if (i < K * 128) {
            int col = i & 127, k = i >> 7;
            T[col * K + k] = f2bf(W[i]);
        }
        return;
    }
    // y == 6: housekeeping
    const int i = blockIdx.x * 256 + threadIdx.x;
    if (i < N) flag[i] = 0;
    if (blockIdx.x == 0) {
        const int t = threadIdx.x;
        bcur[t] = t * TEMPCAP;           // graph o cursors
        bcur[256 + t] = t * TEMPCAP;     // graph s cursors
        if (t == 0) ctr[0] = 0;
    }
}

// ---------------------------------------------------------------------------
// Phase 1: bin edges by row>>9 into fixed-capacity temp slots,
// packed (row&511 | col<<9, val_bits).  Standalone lightweight kernel
// (R14 merge with GEMM regressed: inherited 54KB LDS -> 20% occupancy).
// ---------------------------------------------------------------------------
__global__ __launch_bounds__(256) void binscat1(
    const int* __restrict__ ro, const int* __restrict__ co,
    const float* __restrict__ vo,
    const int* __restrict__ rs, const int* __restrict__ cs,
    const float* __restrict__ vs,
    int* __restrict__ bcur, int2* __restrict__ temp_o,
    int2* __restrict__ temp_s, int E)
{
    const int g = blockIdx.y;
    const int* rows = g ? rs : ro;
    const int* cols = g ? cs : co;
    const float* vals = g ? vs : vo;
    int* bc = bcur + g * 256;
    int2* temp = g ? temp_s : temp_o;

    __shared__ int hist[256];
    __shared__ int base[256];
    const int t = threadIdx.x;
    hist[t] = 0;
    __syncthreads();

    const int e0 = blockIdx.x * SCAT_TILE;
    int myrow[32];
    #pragma unroll
    for (int i = 0; i < 32; ++i) {
        int e = e0 + i * 256 + t;
        int r = (e < E) ? rows[e] : -1;
        myrow[i] = r;
        if (r >= 0) atomicAdd(&hist[r >> BSHIFT], 1);
    }
    __syncthreads();
    const int h = hist[t];
    if (h > 0) base[t] = atomicAdd(&bc[t], h);
    __syncthreads();
    hist[t] = (h > 0) ? base[t] : 0;     // reuse hist as within-block cursor
    __syncthreads();
    #pragma unroll
    for (int i = 0; i < 32; ++i) {
        const int r = myrow[i];
        if (r >= 0) {
            int e = e0 + i * 256 + t;
            int off = atomicAdd(&hist[r >> BSHIFT], 1);
            temp[off] = make_int2((r & 511) | (cols[e] << BSHIFT),
                                  __float_as_int(vals[e]));
        }
    }
}

// ---------------------------------------------------------------------------
// block 0: bucket-base scan from end cursors (count = bcur[b] - b*TEMPCAP).
// blocks 1..: mark needed rows from idx.
// ---------------------------------------------------------------------------
__global__ __launch_bounds__(512) void scan_mark(
    const int* __restrict__ bcur, int* __restrict__ bbase,
    const int* __restrict__ idx, int* __restrict__ flag, int E, int n2)
{
    if (blockIdx.x == 0) {
        __shared__ int sh[256];
        const int t = threadIdx.x;
        for (int g = 0; g < 2; ++g) {
            int v = 0;
            if (t < 256) { v = bcur[g * 256 + t] - t * TEMPCAP; sh[t] = v; }
            __syncthreads();
            for (int off = 1; off < 256; off <<= 1) {
                int u = (t < 256 && t >= off) ? sh[t - off] : 0;
                __syncthreads();
                if (t < 256) sh[t] += u;
                __syncthreads();
            }
            if (t < 256) {
                bbase[g * 257 + t] = sh[t] - v;   // exclusive
                if (t == 255) bbase[g * 257 + 256] = E;
            }
            __syncthreads();
        }
    } else {
        int i = (blockIdx.x - 1) * 512 + threadIdx.x;
        if (i < n2) flag[idx[i]] = 1;
    }
}

// ---------------------------------------------------------------------------
// y<2: per-bucket local counting sort (single temp read; edges staged in
// registers via static unroll). Writes rp + final CSR ev.
// y==2: compact marked rows -> rlist/inv/ctr.
// ---------------------------------------------------------------------------
__global__ __launch_bounds__(512) void bs2_compact(
    const int* __restrict__ bbase,
    const int2* __restrict__ temp_o, const int2* __restrict__ temp_s,
    int* __restrict__ rp_o, int* __restrict__ rp_s,
    int2* __restrict__ ev_o, int2* __restrict__ ev_s,
    const int* __restrict__ flag, int* __restrict__ rlist,
    int* __restrict__ inv, int* __restrict__ ctr, int N)
{
    if (blockIdx.y == 2) {
        int r = blockIdx.x * 512 + threadIdx.x;
        if (r < N && flag[r]) {
            int i = atomicAdd(ctr, 1);
            rlist[i] = r;
            inv[r] = i;
        }
        return;
    }
    const int g = blockIdx.y;
    const int2* temp = g ? temp_s : temp_o;
    int2* ev = g ? ev_s : ev_o;
    int* rp = g ? rp_s : rp_o;
    const int* bb = bbase + g * 257;

    __shared__ int lcnt[512];
    __shared__ int lpre[512];
    const int b = blockIdx.x;
    const int r0 = b << BSHIFT;
    const int t = threadIdx.x;
    const int e0 = bb[b];                      // final CSR base
    const int cntE = bb[b + 1] - e0;           // edges in bucket (<= TEMPCAP)
    const int t0 = b * TEMPCAP;                // temp base

    int2 myed[24];                             // 24*512 = TEMPCAP
    lcnt[t] = 0;
    __syncthreads();
    #pragma unroll
    for (int i = 0; i < 24; ++i) {
        int k = i * 512 + t;
        int2 pk = make_int2(0, 0);
        if (k < cntE) {
            pk = temp[t0 + k];
            atomicAdd(&lcnt[pk.x & 511], 1);
        }
        myed[i] = pk;
    }
    __syncthreads();
    const int v = lcnt[t];
    lpre[t] = v;
    __syncthreads();
    for (int off = 1; off < 512; off <<= 1) {
        int u = (t >= off) ? lpre[t - off] : 0;
        __syncthreads();
        lpre[t] += u;
        __syncthreads();
    }
    const int base = e0 + lpre[t] - v;
    const int r = r0 + t;
    if (r <= N) rp[r] = base;
    __syncthreads();
    lcnt[t] = base;                            // row cursors
    __syncthreads();
    #pragma unroll
    for (int i = 0; i < 24; ++i) {
        int k = i * 512 + t;
        if (k < cntE) {
            int2 pk = myed[i];
            int q = atomicAdd(&lcnt[pk.x & 511], 1);
            ev[q] = make_int2(pk.x >> BSHIFT, pk.y);
        }
    }
}

// ---------------------------------------------------------------------------
// Fused MFMA GEMM: S_m = X @ W_m for NM matrices, X staged ONCE (full K) in LDS.
// 4 waves over a 2x2 (row-half x col-half) grid: 6 LDS b128 reads per 8 MFMA.
// ---------------------------------------------------------------------------
template <int K, int NM, bool XBF>
__global__ __launch_bounds__(256) void gemm_fused(
    const void* __restrict__ Xv,
    const unsigned short* __restrict__ Wt0, unsigned short* __restrict__ S0,
    const unsigned short* __restrict__ Wt1, unsigned short* __restrict__ S1,
    const unsigned short* __restrict__ Wt2, unsigned short* __restrict__ S2,
    int Nrows)
{
    constexpr int AST = K + 8;
    __shared__ unsigned short As[64 * AST];
    __shared__ unsigned short Bs[128 * 72];

    const int t = threadIdx.x;
    const int l = t & 63;
    const int w = t >> 6;
    const int row_in = l & 15;
    const int kgrp = l >> 4;        // 0..3
    const int rhalf = w & 1;
    const int chalf = w >> 1;
    const int row0 = blockIdx.x * 64;

    {
        constexpr int QPR = K / 4;
        #pragma unroll
        for (int it = 0; it < 64 * QPR / 256; ++it) {
            int i = t + it * 256;
            int r = i / QPR, c4 = i % QPR;
            int gr = row0 + r;
            if (XBF) {
                ushort4 v = make_ushort4(0, 0, 0, 0);
                if (gr < Nrows)
                    v = *(const ushort4*)((const unsigned short*)Xv + (size_t)gr * K + c4 * 4);
                *(ushort4*)&As[r * AST + c4 * 4] = v;
            } else {
                float4 v = make_float4(0.f, 0.f, 0.f, 0.f);
                if (gr < Nrows)
                    v = *(const float4*)((const float*)Xv + (size_t)gr * K + c4 * 4);
                ushort4 b4;
                b4.x = f2bf(v.x); b4.y = f2bf(v.y); b4.z = f2bf(v.z); b4.w = f2bf(v.w);
                *(ushort4*)&As[r * AST + c4 * 4] = b4;
            }
        }
    }

    #pragma unroll
    for (int m = 0; m < NM; ++m) {
        const unsigned short* Wt = (m == 0) ? Wt0 : ((m == 1) ? Wt1 : Wt2);
        unsigned short* S = (m == 0) ? S0 : ((m == 1) ? S1 : S2);
        float4v acc[2][4];
        #pragma unroll
        for (int mi = 0; mi < 2; ++mi)
            #pragma unroll
            for (int n = 0; n < 4; ++n) acc[mi][n] = (float4v)(0.f);

        for (int kt = 0; kt < K / 64; ++kt) {
            __syncthreads();
            #pragma unroll
            for (int it = 0; it < 8; ++it) {
                int i = t + it * 256;
                int r = i >> 4, c4 = i & 15;
                *(ushort4*)&Bs[r * 72 + c4 * 4] =
                    *(const ushort4*)(Wt + (size_t)r * K + kt * 64 + c4 * 4);
            }
            __syncthreads();
            #pragma unroll
            for (int kc = 0; kc < 2; ++kc) {
                short8v a[2], b[4];
                #pragma unroll
                for (int mi = 0; mi < 2; ++mi) {
                    const unsigned short* pa =
                        &As[(rhalf * 32 + mi * 16 + row_in) * AST + kt * 64 + kc * 32 + kgrp * 8];
                    ((uint2*)&a[mi])[0] = *(const uint2*)pa;
                    ((uint2*)&a[mi])[1] = *(const uint2*)(pa + 4);
                }
                #pragma unroll
                for (int n = 0; n < 4; ++n) {
                    const unsigned short* pb =
                        &Bs[(chalf * 64 + n * 16 + row_in) * 72 + kc * 32 + kgrp * 8];
                    ((uint2*)&b[n])[0] = *(const uint2*)pb;
                    ((uint2*)&b[n])[1] = *(const uint2*)(pb + 4);
                }
                #pragma unroll
                for (int mi = 0; mi < 2; ++mi)
                    #pragma unroll
                    for (int n = 0; n < 4; ++n)
                        acc[mi][n] = __builtin_amdgcn_mfma_f32_16x16x32_bf16(
                            a[mi], b[n], acc[mi][n], 0, 0, 0);
            }
        }
        #pragma unroll
        for (int mi = 0; mi < 2; ++mi)
            #pragma unroll
            for (int n = 0; n < 4; ++n)
                #pragma unroll
                for (int r = 0; r < 4; ++r) {
                    int gr = row0 + rhalf * 32 + mi * 16 + kgrp * 4 + r;
                    int gc = chalf * 64 + n * 16 + row_in;
                    if (gr < Nrows) S[(size_t)gr * 128 + gc] = f2bf(acc[mi][n][r]);
                }
    }
}

// ---------------------------------------------------------------------------
// GEMM for s_x: sxb = relu(Yo @ Wt4 + Zs + b1 + b2), all K=128, bf16 in/out.
// ---------------------------------------------------------------------------
__global__ __launch_bounds__(256) void gemm_sx(
    const unsigned short* __restrict__ Yo,
    const unsigned short* __restrict__ Wt,
    const unsigned short* __restrict__ Zs,
    const float* __restrict__ b1, const float* __restrict__ b2,
    unsigned short* __restrict__ sxb, int Nrows)
{
    constexpr int AST = 136;
    __shared__ unsigned short As[64 * AST];
    __shared__ unsigned short Bs[128 * 72];

    const int t = threadIdx.x;
    const int l = t & 63;
    const int w = t >> 6;
    const int row_in = l & 15;
    const int kgrp = l >> 4;
    const int rhalf = w & 1;
    const int chalf = w >> 1;
    const int row0 = blockIdx.x * 64;

    #pragma unroll
    for (int it = 0; it < 8; ++it) {        // 64 rows * 32 quads / 256
        int i = t + it * 256;
        int r = i >> 5, c4 = i & 31;
        int gr = row0 + r;
        ushort4 v = make_ushort4(0, 0, 0, 0);
        if (gr < Nrows) v = *(const ushort4*)(Yo + (size_t)gr * 128 + c4 * 4);
        *(ushort4*)&As[r * AST + c4 * 4] = v;
    }

    float4v acc[2][4];
    #pragma unroll
    for (int mi = 0; mi < 2; ++mi)
        #pragma unroll
        for (int n = 0; n < 4; ++n) acc[mi][n] = (float4v)(0.f);

    for (int kt = 0; kt < 2; ++kt) {
        __syncthreads();
        #pragma unroll
        for (int it = 0; it < 8; ++it) {
            int i = t + it * 256;
            int r = i >> 4, c4 = i & 15;
            *(ushort4*)&Bs[r * 72 + c4 * 4] =
                *(const ushort4*)(Wt + (size_t)r * 128 + kt * 64 + c4 * 4);
        }
        __syncthreads();
        #pragma unroll
        for (int kc = 0; kc < 2; ++kc) {
            short8v a[2], b[4];
            #pragma unroll
            for (int mi = 0; mi < 2; ++mi) {
                const unsigned short* pa =
                    &As[(rhalf * 32 + mi * 16 + row_in) * AST + kt * 64 + kc * 32 + kgrp * 8];
                ((uint2*)&a[mi])[0] = *(const uint2*)pa;
                ((uint2*)&a[mi])[1] = *(const uint2*)(pa + 4);
            }
            #pragma unroll
            for (int n = 0; n < 4; ++n) {
                const unsigned short* pb =
                    &Bs[(chalf * 64 + n * 16 + row_in) * 72 + kc * 32 + kgrp * 8];
                ((uint2*)&b[n])[0] = *(const uint2*)pb;
                ((uint2*)&b[n])[1] = *(const uint2*)(pb + 4);
            }
            #pragma unroll
            for (int mi = 0; mi < 2; ++mi)
                #pragma unroll
                for (int n = 0; n < 4; ++n)
                    acc[mi][n] = __builtin_amdgcn_mfma_f32_16x16x32_bf16(
                        a[mi], b[n], acc[mi][n], 0, 0, 0);
        }
    }
    #pragma unroll
    for (int mi = 0; mi < 2; ++mi)
        #pragma unroll
        for (int n = 0; n < 4; ++n)
            #pragma unroll
            for (int r = 0; r < 4; ++r) {
                int gr = row0 + rhalf * 32 + mi * 16 + kgrp * 4 + r;
                int gc = chalf * 64 + n * 16 + row_in;
                if (gr < Nrows) {
                    float vfin = acc[mi][n][r] + bf2f(Zs[(size_t)gr * 128 + gc])
                               + b1[gc] + b2[gc];
                    sxb[(size_t)gr * 128 + gc] = f2bf(fmaxf(vfin, 0.f));
                }
            }
}

// ---------------------------------------------------------------------------
// GEMM for h (compact rows): h[i] = Yo[rlist[i]]@Wt5 + Ys2[i]@Wt6 + b1 + b2
// ---------------------------------------------------------------------------
__global__ __launch_bounds__(256) void gemm_h(
    const unsigned short* __restrict__ Yo, const int* __restrict__ rlist,
    const int* __restrict__ pcnt,
    const unsigned short* __restrict__ Ys2,
    const unsigned short* __restrict__ Wt5, const unsigned short* __restrict__ Wt6,
    const float* __restrict__ b1, const float* __restrict__ b2,
    float* __restrict__ h)
{
    constexpr int AST = 136;
    __shared__ unsigned short As1[64 * AST];
    __shared__ unsigned short As2[64 * AST];
    __shared__ unsigned short Bs[128 * 72];

    const int cnt = *pcnt;
    const int row0 = blockIdx.x * 64;
    if (row0 >= cnt) return;

    const int t = threadIdx.x;
    const int l = t & 63;
    const int w = t >> 6;
    const int row_in = l & 15;
    const int kgrp = l >> 4;
    const int rhalf = w & 1;
    const int chalf = w >> 1;

    #pragma unroll
    for (int it = 0; it < 8; ++it) {
        int i = t + it * 256;
        int r = i >> 5, c4 = i & 31;
        int gr = row0 + r;
        ushort4 v1 = make_ushort4(0, 0, 0, 0);
        ushort4 v2 = make_ushort4(0, 0, 0, 0);
        if (gr < cnt) {
            int src = rlist[gr];
            v1 = *(const ushort4*)(Yo + (size_t)src * 128 + c4 * 4);
            v2 = *(const ushort4*)(Ys2 + (size_t)gr * 128 + c4 * 4);
        }
        *(ushort4*)&As1[r * AST + c4 * 4] = v1;
        *(ushort4*)&As2[r * AST + c4 * 4] = v2;
    }

    float4v acc[2][4];
    #pragma unroll
    for (int mi = 0; mi < 2; ++mi)
        #pragma unroll
        for (int n = 0; n < 4; ++n) acc[mi][n] = (float4v)(0.f);

    #pragma unroll
    for (int pp = 0; pp < 2; ++pp) {
        const unsigned short* Wt = pp ? Wt6 : Wt5;
        const unsigned short* As = pp ? As2 : As1;
        for (int kt = 0; kt < 2; ++kt) {
            __syncthreads();
            #pragma unroll
            for (int it = 0; it < 8; ++it) {
                int i = t + it * 256;
                int r = i >> 4, c4 = i & 15;
                *(ushort4*)&Bs[r * 72 + c4 * 4] =
                    *(const ushort4*)(Wt + (size_t)r * 128 + kt * 64 + c4 * 4);
            }
            __syncthreads();
            #pragma unroll
            for (int kc = 0; kc < 2; ++kc) {
                short8v a[2], b[4];
                #pragma unroll
                for (int mi = 0; mi < 2; ++mi) {
                    const unsigned short* pa =
                        &As[(rhalf * 32 + mi * 16 + row_in) * AST + kt * 64 + kc * 32 + kgrp * 8];
                    ((uint2*)&a[mi])[0] = *(const uint2*)pa;
                    ((uint2*)&a[mi])[1] = *(const uint2*)(pa + 4);
                }
                #pragma unroll
                for (int n = 0; n < 4; ++n) {
                    const unsigned short* pb =
                        &Bs[(chalf * 64 + n * 16 + row_in) * 72 + kc * 32 + kgrp * 8];
                    ((uint2*)&b[n])[0] = *(const uint2*)pb;
                    ((uint2*)&b[n])[1] = *(const uint2*)(pb + 4);
                }
                #pragma unroll
                for (int mi = 0; mi < 2; ++mi)
                    #pragma unroll
                    for (int n = 0; n < 4; ++n)
                        acc[mi][n] = __builtin_amdgcn_mfma_f32_16x16x32_bf16(
                            a[mi], b[n], acc[mi][n], 0, 0, 0);
            }
        }
    }
    #pragma unroll
    for (int mi = 0; mi < 2; ++mi)
        #pragma unroll
        for (int n = 0; n < 4; ++n)
            #pragma unroll
            for (int r = 0; r < 4; ++r) {
                int gr = row0 + rhalf * 32 + mi * 16 + kgrp * 4 + r;
                int gc = chalf * 64 + n * 16 + row_in;
                if (gr < cnt)
                    h[(size_t)gr * 128 + gc] = acc[mi][n][r] + b1[gc] + b2[gc];
            }
}

// ---------------------------------------------------------------------------
// spmm gather helpers
// ---------------------------------------------------------------------------
#define GS(S, pk) (*(const unsigned*)((S) + ((size_t)(pk).x << 7) + l2))
#define ACCV(pk, uu) { float vv = __int_as_float((pk).y); \
    ax = fmaf(vv, asf((uu) << 16), ax); ay = fmaf(vv, asf((uu) & 0xffff0000u), ay); }

// ---------------------------------------------------------------------------
// spmm1: fused dual-graph CSR SpMM with bias+relu, bf16 out (layer 1).
// ---------------------------------------------------------------------------
__global__ __launch_bounds__(256) void spmm1_k(
    const int* __restrict__ rp_a, const int2* __restrict__ ev_a,
    const unsigned short* __restrict__ Sa,
    const int* __restrict__ rp_b, const int2* __restrict__ ev_b,
    const unsigned short* __restrict__ Sb,
    const float* __restrict__ b1, const float* __restrict__ b2,
    unsigned short* __restrict__ out, int N)
{
    const int row = blockIdx.x * 4 + (threadIdx.x >> 6);
    if (row >= N) return;
    const int l2 = (threadIdx.x & 63) << 1;

    float2 bv1 = *(const float2*)(b1 + l2);
    float2 bv2 = *(const float2*)(b2 + l2);
    float ax = bv1.x + bv2.x;
    float ay = bv1.y + bv2.y;

    #pragma unroll
    for (int g = 0; g < 2; ++g) {
        const int* __restrict__ rp = g ? rp_b : rp_a;
        const int2* __restrict__ ev = g ? ev_b : ev_a;
        const unsigned short* __restrict__ S = g ? Sb : Sa;
        int e = rp[row];
        const int e1 = rp[row + 1];
        for (; e + 8 <= e1; e += 8) {
            const int2 p0 = ev[e], p1 = ev[e+1], p2 = ev[e+2], p3 = ev[e+3];
            const int2 p4 = ev[e+4], p5 = ev[e+5], p6 = ev[e+6], p7 = ev[e+7];
            const unsigned u0 = GS(S,p0), u1 = GS(S,p1), u2 = GS(S,p2), u3 = GS(S,p3);
            const unsigned u4 = GS(S,p4), u5 = GS(S,p5), u6 = GS(S,p6), u7 = GS(S,p7);
            ACCV(p0,u0) ACCV(p1,u1) ACCV(p2,u2) ACCV(p3,u3)
            ACCV(p4,u4) ACCV(p5,u5) ACCV(p6,u6) ACCV(p7,u7)
        }
        for (; e + 4 <= e1; e += 4) {
            const int2 p0 = ev[e], p1 = ev[e+1], p2 = ev[e+2], p3 = ev[e+3];
            const unsigned u0 = GS(S,p0), u1 = GS(S,p1), u2 = GS(S,p2), u3 = GS(S,p3);
            ACCV(p0,u0) ACCV(p1,u1) ACCV(p2,u2) ACCV(p3,u3)
        }
        for (; e < e1; ++e) {
            const int2 p0 = ev[e];
            const unsigned u0 = GS(S,p0);
            ACCV(p0,u0)
        }
    }
    ax = fmaxf(ax, 0.f); ay = fmaxf(ay, 0.f);
    unsigned pk = (unsigned)f2bf(ax) | ((unsigned)f2bf(ay) << 16);
    ((unsigned*)out)[((size_t)row << 6) + (l2 >> 1)] = pk;
}

// ---------------------------------------------------------------------------
// spmm_split: Yo = A_o * oxb, Zs = A_s * tabC (no bias, no relu), bf16 out.
// ---------------------------------------------------------------------------
__global__ __launch_bounds__(256) void spmm_split(
    const int* __restrict__ rp_a, const int2* __restrict__ ev_a,
    const unsigned short* __restrict__ Sa,
    const int* __restrict__ rp_b, const int2* __restrict__ ev_b,
    const unsigned short* __restrict__ Sb,
    unsigned short* __restrict__ Yo, unsigned short* __restrict__ Zs, int N)
{
    const int row = blockIdx.x * 4 + (threadIdx.x >> 6);
    if (row >= N) return;
    const int l2 = (threadIdx.x & 63) << 1;

    #pragma unroll
    for (int g = 0; g < 2; ++g) {
        const int* __restrict__ rp = g ? rp_b : rp_a;
        const int2* __restrict__ ev = g ? ev_b : ev_a;
        const unsigned short* __restrict__ S = g ? Sb : Sa;
        unsigned short* __restrict__ out = g ? Zs : Yo;
        float ax = 0.f, ay = 0.f;
        int e = rp[row];
        const int e1 = rp[row + 1];
        for (; e + 8 <= e1; e += 8) {
            const int2 p0 = ev[e], p1 = ev[e+1], p2 = ev[e+2], p3 = ev[e+3];
            const int2 p4 = ev[e+4], p5 = ev[e+5], p6 = ev[e+6], p7 = ev[e+7];
            const unsigned u0 = GS(S,p0), u1 = GS(S,p1), u2 = GS(S,p2), u3 = GS(S,p3);
            const unsigned u4 = GS(S,p4), u5 = GS(S,p5), u6 = GS(S,p6), u7 = GS(S,p7);
            ACCV(p0,u0) ACCV(p1,u1) ACCV(p2,u2) ACCV(p3,u3)
            ACCV(p4,u4) ACCV(p5,u5) ACCV(p6,u6) ACCV(p7,u7)
        }
        for (; e + 4 <= e1; e += 4) {
            const int2 p0 = ev[e], p1 = ev[e+1], p2 = ev[e+2], p3 = ev[e+3];
            const unsigned u0 = GS(S,p0), u1 = GS(S,p1), u2 = GS(S,p2), u3 = GS(S,p3);
            ACCV(p0,u0) ACCV(p1,u1) ACCV(p2,u2) ACCV(p3,u3)
        }
        for (; e < e1; ++e) {
            const int2 p0 = ev[e];
            const unsigned u0 = GS(S,p0);
            ACCV(p0,u0)
        }
        unsigned pk = (unsigned)f2bf(ax) | ((unsigned)f2bf(ay) << 16);
        ((unsigned*)out)[((size_t)row << 6) + (l2 >> 1)] = pk;
    }
}

// ---------------------------------------------------------------------------
// spmm_s_sparse: Ys2[i] = A_s * sxb at row rlist[i], bf16 compact out.
// (standalone: 32768 rows in flight; fusing into gemm_h regressed in R15)
// ---------------------------------------------------------------------------
__global__ __launch_bounds__(256) void spmm_s_sparse(
    const int* __restrict__ rp, const int2* __restrict__ ev,
    const unsigned short* __restrict__ S,
    const int* __restrict__ rlist, const int* __restrict__ pcnt,
    unsigned short* __restrict__ out)
{
    const int gi = blockIdx.x * 4 + (threadIdx.x >> 6);
    if (gi >= *pcnt) return;
    const int row = rlist[gi];
    const int l2 = (threadIdx.x & 63) << 1;

    float ax = 0.f, ay = 0.f;
    int e = rp[row];
    const int e1 = rp[row + 1];
    for (; e + 8 <= e1; e += 8) {
        const int2 p0 = ev[e], p1 = ev[e+1], p2 = ev[e+2], p3 = ev[e+3];
        const int2 p4 = ev[e+4], p5 = ev[e+5], p6 = ev[e+6], p7 = ev[e+7];
        const unsigned u0 = GS(S,p0), u1 = GS(S,p1), u2 = GS(S,p2), u3 = GS(S,p3);
        const unsigned u4 = GS(S,p4), u5 = GS(S,p5), u6 = GS(S,p6), u7 = GS(S,p7);
        ACCV(p0,u0) ACCV(p1,u1) ACCV(p2,u2) ACCV(p3,u3)
        ACCV(p4,u4) ACCV(p5,u5) ACCV(p6,u6) ACCV(p7,u7)
    }
    for (; e + 4 <= e1; e += 4) {
        const int2 p0 = ev[e], p1 = ev[e+1], p2 = ev[e+2], p3 = ev[e+3];
        const unsigned u0 = GS(S,p0), u1 = GS(S,p1), u2 = GS(S,p2), u3 = GS(S,p3);
        ACCV(p0,u0) ACCV(p1,u1) ACCV(p2,u2) ACCV(p3,u3)
    }
    for (; e < e1; ++e) {
        const int2 p0 = ev[e];
        const unsigned u0 = GS(S,p0);
        ACCV(p0,u0)
    }
    unsigned pk = (unsigned)f2bf(ax) | ((unsigned)f2bf(ay) << 16);
    ((unsigned*)out)[((size_t)gi << 6) + (l2 >> 1)] = pk;
}
#undef GS
#undef ACCV

// ---------------------------------------------------------------------------
// Fused decoder: o1 tile stays in LDS between the two small GEMMs.
// ---------------------------------------------------------------------------
__global__ __launch_bounds__(128) void dec_fused(
    const float* __restrict__ h, const int* __restrict__ inv,
    const int* __restrict__ idx0, const int* __restrict__ idx1,
    const float* __restrict__ Wd1, const float* __restrict__ bd1,
    const float* __restrict__ Wd2, const float* __restrict__ bd2,
    float* __restrict__ out, int B)
{
    __shared__ __align__(16) float fs[16 * 256];
    __shared__ __align__(16) float os[16 * 128];
    const int t = threadIdx.x;
    const int b0 = blockIdx.x * 16;
    #pragma unroll
    for (int r = 0; r < 16; ++r) {
        const int b = b0 + r;
        fs[r * 256 + t]       = h[(long)inv[idx0[b]] * 128 + t];
        fs[r * 256 + 128 + t] = h[(long)inv[idx1[b]] * 128 + t];
    }
    __syncthreads();

    {
        const float4* fs4 = (const float4*)fs;
        float acc[16];
        #pragma unroll
        for (int r = 0; r < 16; ++r) acc[r] = 0.f;
        for (int kc = 0; kc < 64; ++kc) {
            const float w0 = Wd1[(kc * 4 + 0) * 128 + t];
            const float w1 = Wd1[(kc * 4 + 1) * 128 + t];
            const float w2 = Wd1[(kc * 4 + 2) * 128 + t];
            const float w3 = Wd1[(kc * 4 + 3) * 128 + t];
            #pragma unroll
            for (int r = 0; r < 16; ++r) {
                const float4 xv = fs4[r * 64 + kc];
                acc[r] = fmaf(xv.x, w0, acc[r]);
                acc[r] = fmaf(xv.y, w1, acc[r]);
                acc[r] = fmaf(xv.z, w2, acc[r]);
                acc[r] = fmaf(xv.w, w3, acc[r]);
            }
        }
        #pragma unroll
        for (int r = 0; r < 16; ++r)
            os[r * 128 + t] = acc[r] + bd1[t];
    }
    __syncthreads();

    {
        const float4* os4 = (const float4*)os;
        float acc[16];
        #pragma unroll
        for (int r = 0; r < 16; ++r) acc[r] = 0.f;
        const bool act = (t < RELL);
        for (int kc = 0; kc < 32; ++kc) {
            const float w0 = act ? Wd2[(kc * 4 + 0) * RELL + t] : 0.f;
            const float w1 = act ? Wd2[(kc * 4 + 1) * RELL + t] : 0.f;
            const float w2 = act ? Wd2[(kc * 4 + 2) * RELL + t] : 0.f;
            const float w3 = act ? Wd2[(kc * 4 + 3) * RELL + t] : 0.f;
            #pragma unroll
            for (int r = 0; r < 16; ++r) {
                const float4 xv = os4[r * 32 + kc];
                acc[r] = fmaf(xv.x, w0, acc[r]);
                acc[r] = fmaf(xv.y, w1, acc[r]);
                acc[r] = fmaf(xv.z, w2, acc[r]);
                acc[r] = fmaf(xv.w, w3, acc[r]);
            }
        }
        if (act) {
            #pragma unroll
            for (int r = 0; r < 16; ++r)
                out[(long)(b0 + r) * RELL + t] = acc[r] + bd2[t];
        }
    }
}

extern "C" void kernel_launch(void* const* d_in, const int* in_sizes, int n_in,
                              void* d_out, int out_size, void* d_ws, size_t ws_size,
                              hipStream_t stream) {
    const float* x      = (const float*)d_in[0];
    const int*   o_rows = (const int*)  d_in[1];
    const int*   o_cols = (const int*)  d_in[2];
    const float* o_vals = (const float*)d_in[3];
    const int*   s_rows = (const int*)  d_in[4];
    const int*   s_cols = (const int*)  d_in[5];
    const float* s_vals = (const float*)d_in[6];
    const int*   idx    = (const int*)  d_in[7];
    const float* W_ogc1  = (const float*)d_in[8];   const float* b_ogc1  = (const float*)d_in[9];
    const float* W_sgc1o = (const float*)d_in[10];  const float* b_sgc1o = (const float*)d_in[11];
    const float* W_sgc1  = (const float*)d_in[12];  const float* b_sgc1  = (const float*)d_in[13];
    const float* W_ogc1s = (const float*)d_in[14];  const float* b_ogc1s = (const float*)d_in[15];
    const float* W_ogc2  = (const float*)d_in[16];  const float* b_ogc2  = (const float*)d_in[17];
    const float* W_sgc2o = (const float*)d_in[18];  const float* b_sgc2o = (const float*)d_in[19];
    const float* W_dec1  = (const float*)d_in[20];  const float* b_dec1  = (const float*)d_in[21];
    const float* W_dec2  = (const float*)d_in[22];  const float* b_dec2  = (const float*)d_in[23];

    const int N = in_sizes[0] / NFEAT;   // 100000
    const int E = in_sizes[1];           // 1600000
    const int B = in_sizes[7] / 2;       // 16384
    const int* idx0 = idx;
    const int* idx1 = idx + B;

    // ---- workspace layout (float units) ----
    float* p = (float*)d_ws;
    const size_t N64 = (size_t)N * 64;    // one bf16 [N,128] table in float units
    float* h    = p;  p += (size_t)2 * B * 128;      // compact fp32 [<=2B,128]
    unsigned short* oxb  = (unsigned short*)p; p += N64;   // o_x bf16
    unsigned short* sxb  = (unsigned short*)p; p += N64;   // s_x bf16
    unsigned short* tabA = (unsigned short*)p; p += N64;
    unsigned short* tabB = (unsigned short*)p; p += N64;
    unsigned short* tabC = (unsigned short*)p; p += N64;
    unsigned short* Yo   = (unsigned short*)p; p += N64;   // A_o * o_x
    unsigned short* Zs   = (unsigned short*)p; p += N64;   // A_s * tabC
    unsigned short* Ys2  = (unsigned short*)p; p += (size_t)2 * B * 64;  // compact A_s*s_x
    unsigned short* wt1 = (unsigned short*)p; p += 16384;   // [128,256] bf16
    unsigned short* wt2 = (unsigned short*)p; p += 16384;
    unsigned short* wt3 = (unsigned short*)p; p += 16384;
    unsigned short* wt4 = (unsigned short*)p; p += 8192;    // [128,128] bf16
    unsigned short* wt5 = (unsigned short*)p; p += 8192;
    unsigned short* wt6 = (unsigned short*)p; p += 8192;
    int* rp_o = (int*)p; p += (size_t)N + 2;
    int* rp_s = (int*)p; p += (size_t)N + 2;
    int2* ev_o = (int2*)p; p += 2 * (size_t)E;
    int2* ev_s = (int2*)p; p += 2 * (size_t)E;
    int* bbase = (int*)p; p += 516;                  // [2][257] bucket bases
    int* bcur  = (int*)p; p += 512;                  // [2][256] bucket cursors
    int* flag  = (int*)p; p += (size_t)N;            // needed-row flags
    int* rlist = (int*)p; p += (size_t)N;            // compact row list
    int* inv   = (int*)p; p += (size_t)N;            // node -> compact index
    int* ctr   = (int*)p; p += 2;                    // compact count
    // temp binning buffers alias tabA/tabB (dead until first GEMM)
    int2* temp_o = (int2*)tabA;                      // 256*TEMPCAP int2 = 25.2 MB
    int2* temp_s = (int2*)tabB;

    const int gM64 = (N + 63) / 64;       // 1563
    const int gR = (N + 3) / 4;           // 25000
    const int gRs = (2 * B + 3) / 4;      // 8192 (sparse rows <= 2B)
    const int gH = (2 * B + 63) / 64;     // 512
    const int gB = B / 16;                // 1024
    const int gT = (E + SCAT_TILE - 1) / SCAT_TILE;                   // 196
    const int gBuck = (N + (1 << BSHIFT) - 1) >> BSHIFT;              // 196
    const int gFlag = (N + 255) / 256;                                // 391
    const int gMark = (2 * B + 511) / 512;                            // 64

    // ---- init + weight prep
    init_prep<<<dim3(gFlag, 7), 256, 0, stream>>>(
        W_ogc1, W_sgc1o, W_sgc1, W_ogc1s, W_ogc2, W_sgc2o,
        wt1, wt2, wt3, wt4, wt5, wt6, bcur, flag, ctr, N);

    // ---- CSR build (both graphs via y-grid)
    binscat1<<<dim3(gT, 2), 256, 0, stream>>>(o_rows, o_cols, o_vals,
                                              s_rows, s_cols, s_vals,
                                              bcur, temp_o, temp_s, E);
    scan_mark<<<1 + gMark, 512, 0, stream>>>(bcur, bbase, idx, flag, E, 2 * B);
    bs2_compact<<<dim3(gBuck, 3), 512, 0, stream>>>(
        bbase, temp_o, temp_s, rp_o, rp_s, ev_o, ev_s,
        flag, rlist, inv, ctr, N);

    // ---- Layer 1 GEMMs (x read once): tabA=x@W_ogc1, tabB=x@W_sgc1o, tabC=x@W_sgc1
    gemm_fused<NFEAT, 3, false><<<gM64, 256, 0, stream>>>(
        x, wt1, tabA, wt2, tabB, wt3, tabC, N);
    spmm1_k<<<gR, 256, 0, stream>>>(rp_o, ev_o, tabA, rp_s, ev_s, tabB,
                                    b_ogc1, b_sgc1o, oxb, N);        // o_x

    // ---- spmm_split: Yo = A_o*o_x, Zs = A_s*tabC  (serves layers 2 AND 3)
    spmm_split<<<gR, 256, 0, stream>>>(rp_o, ev_o, oxb, rp_s, ev_s, tabC,
                                       Yo, Zs, N);

    // ---- s_x = relu(Yo@W_ogc1s + Zs + b_ogc1s + b_sgc1)
    gemm_sx<<<gM64, 256, 0, stream>>>(Yo, wt4, Zs, b_ogc1s, b_sgc1, sxb, N);

    // ---- Ys2 = A_s*s_x (sparse rows); h = Yo[rlist]@W_ogc2 + Ys2@W_sgc2o + b
    spmm_s_sparse<<<gRs, 256, 0, stream>>>(rp_s, ev_s, sxb, rlist, ctr, Ys2);
    gemm_h<<<gH, 256, 0, stream>>>(Yo, rlist, ctr, Ys2, wt5, wt6,
                                   b_ogc2, b_sgc2o, h);

    // ---- Fused decoder
    dec_fused<<<gB, 128, 0, stream>>>(h, inv, idx0, idx1,
                                      W_dec1, b_dec1, W_dec2, b_dec2,
                                      (float*)d_out, B);
}